// Round 1
// 377.078 us; speedup vs baseline: 1.0025x; 1.0025x over previous
//
#include <hip/hip_runtime.h>

// SparseVoxelEncoder: trilinear interpolation of 8 corner embeddings per point.
// out[p, :] = sum_{c=0}^{7} w_c(p) * values[point_feats[sampled_idx[p]][c], :]
//
// Layout: 8 lanes per point; lane `sub` owns float4 chunk d[4*sub..4*sub+3].
// Each corner read is one coalesced 128-B cacheline (8 lanes x 16 B).
// Corner order matches jax meshgrid 'ij': c bits = (x=c>>2, y=(c>>1)&1, z=c&1).
//
// R4 change: out stores go through inline-asm `global_store_dwordx4 ... nt sc0 sc1`
// (full streaming / system-scope / non-temporal policy). Theory: the 134 MB
// write-once out stream allocates in the 256 MB memory-side Infinity Cache and
// evicts the 76.8 MB `values` table (within-dispatch hot set was ~249 MB ~= L3),
// causing ~525 MB of HBM re-fetch on the values gather. __builtin_nontemporal_store
// (R2/R3) only sets `nt` and did NOT reduce FETCH_SIZE (639->641 MB); the scope
// bits sc0+sc1 are only reachable via asm.

#define VOXEL_INV 4.0f  // 1 / 0.25

typedef float vfloat4 __attribute__((ext_vector_type(4)));

__device__ __forceinline__ void store_stream_f4(float* addr, vfloat4 v)
{
    // addr first, then data (gfx9 global_store operand order).
    asm volatile("global_store_dwordx4 %0, %1, off nt sc0 sc1"
                 :
                 : "v"(addr), "v"(v)
                 : "memory");
}

__global__ __launch_bounds__(256) void svenc_kernel(
    const float* __restrict__ sampled_xyz,   // [P,3]
    const float* __restrict__ point_xyz,     // [H,3]
    const float* __restrict__ values,        // [NEMB,32]
    const int*   __restrict__ sampled_idx,   // [P]
    const int*   __restrict__ point_feats,   // [H,8]
    float*       __restrict__ out,           // [P,32]
    int P)
{
    int t   = blockIdx.x * blockDim.x + threadIdx.x;
    int pid = t >> 3;       // point index
    int sub = t & 7;        // which float4 chunk of the 32-float row
    if (pid >= P) return;

    // read-once streams -> non-temporal (don't pollute L2/L3)
    int vi = __builtin_nontemporal_load(sampled_idx + pid);

    float sx = __builtin_nontemporal_load(sampled_xyz + pid * 3 + 0);
    float sy = __builtin_nontemporal_load(sampled_xyz + pid * 3 + 1);
    float sz = __builtin_nontemporal_load(sampled_xyz + pid * 3 + 2);

    // ~2x-reuse tables -> normal cached path
    float cx = point_xyz[(size_t)vi * 3 + 0];
    float cy = point_xyz[(size_t)vi * 3 + 1];
    float cz = point_xyz[(size_t)vi * 3 + 2];

    float px = (sx - cx) * VOXEL_INV + 0.5f;
    float py = (sy - cy) * VOXEL_INV + 0.5f;
    float pz = (sz - cz) * VOXEL_INV + 0.5f;

    float xs[2] = {1.0f - px, px};
    float ys[2] = {1.0f - py, py};
    float zs[2] = {1.0f - pz, pz};

    // 8 corner embedding ids: two int4 loads (32-B aligned row)
    const int4* pf4 = (const int4*)(point_feats + ((size_t)vi << 3));
    int4 f0 = pf4[0];
    int4 f1 = pf4[1];
    int ids[8] = {f0.x, f0.y, f0.z, f0.w, f1.x, f1.y, f1.z, f1.w};

    vfloat4 acc = {0.0f, 0.0f, 0.0f, 0.0f};
#pragma unroll
    for (int c = 0; c < 8; ++c) {
        float w = xs[(c >> 2) & 1] * ys[(c >> 1) & 1] * zs[c & 1];
        const vfloat4 v = ((const vfloat4*)(values + ((size_t)ids[c] << 5)))[sub];
        acc += w * v;
    }

    // write-once output -> full streaming policy (nt + system scope):
    // do not allocate in L2 or the memory-side Infinity Cache.
    store_stream_f4(out + ((size_t)pid << 5) + ((size_t)sub << 2), acc);
}

extern "C" void kernel_launch(void* const* d_in, const int* in_sizes, int n_in,
                              void* d_out, int out_size, void* d_ws, size_t ws_size,
                              hipStream_t stream) {
    const float* sampled_xyz = (const float*)d_in[0];
    const float* point_xyz   = (const float*)d_in[1];
    const float* values      = (const float*)d_in[2];
    const int*   sampled_idx = (const int*)d_in[3];
    const int*   point_feats = (const int*)d_in[4];
    float* out = (float*)d_out;

    int P = in_sizes[3];            // number of sampled points
    long total_threads = (long)P * 8;
    int block = 256;
    int grid = (int)((total_threads + block - 1) / block);

    svenc_kernel<<<grid, block, 0, stream>>>(
        sampled_xyz, point_xyz, values, sampled_idx, point_feats, out, P);
}